// Round 1
// baseline (1257.524 us; speedup 1.0000x reference)
//
#include <hip/hip_runtime.h>

// Problem constants
#define BB 2
#define NN 4
#define DD 48
#define HH 28
#define WW 60
#define CC 64
#define NXg 192
#define NYg 192
#define NZg 1
#define DOWNS 8

constexpr int PTS = BB * NN * DD * HH * WW;          // 645120 points
constexpr int CH_STRIDE = NYg * NXg;                 // 36864 (channel stride in out)

// ---------------------------------------------------------------------------
// Kernel A: per-point geometry -> flat base index (or -1 if culled).
// Computed in double to minimize cell-boundary mismatches vs the f32 reference.
// ---------------------------------------------------------------------------
__global__ void geom_kernel(const float* __restrict__ intr,
                            const float* __restrict__ pose,
                            int* __restrict__ sidx) {
    int p = blockIdx.x * blockDim.x + threadIdx.x;
    if (p >= PTS) return;

    int w = p % WW;
    int t = p / WW;
    int h = t % HH; t /= HH;
    int d = t % DD; t /= DD;
    int n = t % NN;
    int b = t / NN;

    const float* K  = intr + (size_t)(b * NN + n) * 9;
    const float* Pm = pose + (size_t)(b * NN + n) * 16;

    double k00 = K[0], k01 = K[1], k02 = K[2];
    double k10 = K[3], k11 = K[4], k12 = K[5];
    double k20 = K[6], k21 = K[7], k22 = K[8];

    // adjugate / det inverse
    double det = k00 * (k11 * k22 - k12 * k21)
               - k01 * (k10 * k22 - k12 * k20)
               + k02 * (k10 * k21 - k11 * k20);
    double id = 1.0 / det;
    double i00 = (k11 * k22 - k12 * k21) * id;
    double i01 = (k02 * k21 - k01 * k22) * id;
    double i02 = (k01 * k12 - k02 * k11) * id;
    double i10 = (k12 * k20 - k10 * k22) * id;
    double i11 = (k00 * k22 - k02 * k20) * id;
    double i12 = (k02 * k10 - k00 * k12) * id;
    double i20 = (k10 * k21 - k11 * k20) * id;
    double i21 = (k01 * k20 - k00 * k21) * id;
    double i22 = (k00 * k11 - k01 * k10) * id;

    // combine = R @ Kinv ; R = pose[:3,:3], trans = pose[:3,3]
    double r00 = Pm[0],  r01 = Pm[1],  r02 = Pm[2],  tx = Pm[3];
    double r10 = Pm[4],  r11 = Pm[5],  r12 = Pm[6],  ty = Pm[7];
    double r20 = Pm[8],  r21 = Pm[9],  r22 = Pm[10], tz = Pm[11];

    double c00 = r00 * i00 + r01 * i10 + r02 * i20;
    double c01 = r00 * i01 + r01 * i11 + r02 * i21;
    double c02 = r00 * i02 + r01 * i12 + r02 * i22;
    double c10 = r10 * i00 + r11 * i10 + r12 * i20;
    double c11 = r10 * i01 + r11 * i11 + r12 * i21;
    double c12 = r10 * i02 + r11 * i12 + r12 * i22;
    double c20 = r20 * i00 + r21 * i10 + r22 * i20;
    double c21 = r20 * i01 + r21 * i11 + r22 * i21;
    double c22 = r20 * i02 + r21 * i12 + r22 * i22;

    // frustum point
    double u   = (double)w * ((double)(WW * DOWNS - 1) / (double)(WW - 1));
    double v   = (double)h * ((double)(HH * DOWNS - 1) / (double)(HH - 1));
    double dep = 2.0 + (double)d;   // DMIN + d*DSTEP
    double px = u * dep, py = v * dep, pz = dep;

    double gxf = (c00 * px + c01 * py + c02 * pz + tx) * 4.0 + 96.0;  // f_bev, cx_bev
    double gyf = (c10 * px + c11 * py + c12 * pz + ty) * 4.0 + 96.0;  // cy_bev
    double gzf = ((c20 * px + c21 * py + c22 * pz + tz) + 10.0) / 20.0;

    // truncation toward zero, same as .astype(int32)
    int gx = (int)gxf;
    int gy = (int)gyf;
    int gz = (int)gzf;

    bool kept = (gx >= 0) & (gx < NXg) & (gy >= 0) & (gy < NYg) &
                (gz >= 0) & (gz < NZg);

    // out layout: (B, NZ*C, NY, NX); base index at channel 0
    int s = kept ? ((((b * NZg + gz) * CC) * NYg + gy) * NXg + gx) : -1;
    sidx[p] = s;
}

// ---------------------------------------------------------------------------
// Kernel B: one wave per point, lane = channel. Wave-uniform cull skip.
// ---------------------------------------------------------------------------
__global__ void scatter_kernel(const float* __restrict__ x,
                               const int* __restrict__ sidx,
                               float* __restrict__ out) {
    int wave = blockIdx.x * (blockDim.x >> 6) + (threadIdx.x >> 6);
    int lane = threadIdx.x & 63;
    if (wave >= PTS) return;

    int s = sidx[wave];          // all 64 lanes same dword -> broadcast
    if (s < 0) return;           // wave-uniform branch: skip culled point

    float val = x[(size_t)wave * CC + lane];   // coalesced 256B
    atomicAdd(out + (size_t)s + (size_t)lane * CH_STRIDE, val);
}

// ---------------------------------------------------------------------------
extern "C" void kernel_launch(void* const* d_in, const int* in_sizes, int n_in,
                              void* d_out, int out_size, void* d_ws, size_t ws_size,
                              hipStream_t stream) {
    const float* x    = (const float*)d_in[0];
    const float* intr = (const float*)d_in[1];
    const float* pose = (const float*)d_in[2];
    float* out = (float*)d_out;
    int* sidx  = (int*)d_ws;     // PTS * 4 bytes = 2.58 MB

    hipMemsetAsync(d_out, 0, (size_t)out_size * sizeof(float), stream);

    geom_kernel<<<(PTS + 255) / 256, 256, 0, stream>>>(intr, pose, sidx);

    // 4 waves (= 4 points) per 256-thread block
    scatter_kernel<<<PTS / 4, 256, 0, stream>>>(x, sidx, out);
}

// Round 2
// 407.472 us; speedup vs baseline: 3.0862x; 3.0862x over previous
//
#include <hip/hip_runtime.h>

// Problem constants
#define BB 2
#define NN 4
#define DD 48
#define HH 28
#define WW 60
#define CC 64
#define NXg 192
#define NYg 192
#define NZg 1
#define DOWNS 8

constexpr int PTS    = BB * NN * DD * HH * WW;       // 645120 points
constexpr int NCELLS = BB * NZg * NYg * NXg;         // 73728 output cells
constexpr int CH_STRIDE = NYg * NXg;                 // 36864 floats per channel plane

// ---------------------------------------------------------------------------
// Kernel A: per-point geometry -> cell id (or -1), plus histogram.
// f64 to minimize cell-boundary mismatches vs the f32 numpy reference.
// ---------------------------------------------------------------------------
__global__ void geom_hist_kernel(const float* __restrict__ intr,
                                 const float* __restrict__ pose,
                                 int* __restrict__ sidx,
                                 int* __restrict__ counts) {
    int p = blockIdx.x * blockDim.x + threadIdx.x;
    if (p >= PTS) return;

    int w = p % WW;
    int t = p / WW;
    int h = t % HH; t /= HH;
    int d = t % DD; t /= DD;
    int n = t % NN;
    int b = t / NN;

    const float* K  = intr + (size_t)(b * NN + n) * 9;
    const float* Pm = pose + (size_t)(b * NN + n) * 16;

    double k00 = K[0], k01 = K[1], k02 = K[2];
    double k10 = K[3], k11 = K[4], k12 = K[5];
    double k20 = K[6], k21 = K[7], k22 = K[8];

    double det = k00 * (k11 * k22 - k12 * k21)
               - k01 * (k10 * k22 - k12 * k20)
               + k02 * (k10 * k21 - k11 * k20);
    double id = 1.0 / det;
    double i00 = (k11 * k22 - k12 * k21) * id;
    double i01 = (k02 * k21 - k01 * k22) * id;
    double i02 = (k01 * k12 - k02 * k11) * id;
    double i10 = (k12 * k20 - k10 * k22) * id;
    double i11 = (k00 * k22 - k02 * k20) * id;
    double i12 = (k02 * k10 - k00 * k12) * id;
    double i20 = (k10 * k21 - k11 * k20) * id;
    double i21 = (k01 * k20 - k00 * k21) * id;
    double i22 = (k00 * k11 - k01 * k10) * id;

    double r00 = Pm[0],  r01 = Pm[1],  r02 = Pm[2],  tx = Pm[3];
    double r10 = Pm[4],  r11 = Pm[5],  r12 = Pm[6],  ty = Pm[7];
    double r20 = Pm[8],  r21 = Pm[9],  r22 = Pm[10], tz = Pm[11];

    double c00 = r00 * i00 + r01 * i10 + r02 * i20;
    double c01 = r00 * i01 + r01 * i11 + r02 * i21;
    double c02 = r00 * i02 + r01 * i12 + r02 * i22;
    double c10 = r10 * i00 + r11 * i10 + r12 * i20;
    double c11 = r10 * i01 + r11 * i11 + r12 * i21;
    double c12 = r10 * i02 + r11 * i12 + r12 * i22;
    double c20 = r20 * i00 + r21 * i10 + r22 * i20;
    double c21 = r20 * i01 + r21 * i11 + r22 * i21;
    double c22 = r20 * i02 + r21 * i12 + r22 * i22;

    double u   = (double)w * ((double)(WW * DOWNS - 1) / (double)(WW - 1));
    double v   = (double)h * ((double)(HH * DOWNS - 1) / (double)(HH - 1));
    double dep = 2.0 + (double)d;
    double px = u * dep, py = v * dep, pz = dep;

    double gxf = (c00 * px + c01 * py + c02 * pz + tx) * 4.0 + 96.0;
    double gyf = (c10 * px + c11 * py + c12 * pz + ty) * 4.0 + 96.0;
    double gzf = ((c20 * px + c21 * py + c22 * pz + tz) + 10.0) / 20.0;

    int gx = (int)gxf;
    int gy = (int)gyf;
    int gz = (int)gzf;

    bool kept = (gx >= 0) & (gx < NXg) & (gy >= 0) & (gy < NYg) &
                (gz >= 0) & (gz < NZg);

    int cell = kept ? (((b * NZg + gz) * NYg + gy) * NXg + gx) : -1;
    sidx[p] = cell;
    if (kept) atomicAdd(&counts[cell], 1);
}

// ---------------------------------------------------------------------------
// Kernel B: single-block exclusive scan of counts (73728 = 72 * 1024).
// Writes offsets[] (stable) and cursor[] (working copy for the fill pass).
// ---------------------------------------------------------------------------
__global__ void scan_kernel(const int* __restrict__ counts,
                            int* __restrict__ offsets,
                            int* __restrict__ cursor) {
    __shared__ int wsum[16];
    __shared__ int wbase[16];
    __shared__ int carry;
    int tid  = threadIdx.x;
    int lane = tid & 63, wid = tid >> 6;
    if (tid == 0) carry = 0;
    __syncthreads();

    for (int chunk = 0; chunk < NCELLS / 1024; ++chunk) {
        int i = chunk * 1024 + tid;
        int v = counts[i];
        int incl = v;
        #pragma unroll
        for (int o = 1; o < 64; o <<= 1) {
            int t = __shfl_up(incl, o, 64);
            if (lane >= o) incl += t;
        }
        if (lane == 63) wsum[wid] = incl;
        __syncthreads();
        if (tid == 0) {
            int run = carry;
            #pragma unroll
            for (int k = 0; k < 16; ++k) { int t = wsum[k]; wbase[k] = run; run += t; }
            carry = run;
        }
        __syncthreads();
        int excl = wbase[wid] + incl - v;
        offsets[i] = excl;
        cursor[i]  = excl;
        __syncthreads();   // protect wsum/wbase before next chunk
    }
}

// ---------------------------------------------------------------------------
// Kernel C: fill bins with point ids (order within a cell is arbitrary).
// ---------------------------------------------------------------------------
__global__ void fill_kernel(const int* __restrict__ sidx,
                            int* __restrict__ cursor,
                            int* __restrict__ bins) {
    int p = blockIdx.x * blockDim.x + threadIdx.x;
    if (p >= PTS) return;
    int cell = sidx[p];
    if (cell < 0) return;
    int idx = atomicAdd(&cursor[cell], 1);
    bins[idx] = p;
}

// ---------------------------------------------------------------------------
// Kernel D: one wave per cell, lane = channel. Register-accumulate, one store.
// ---------------------------------------------------------------------------
__global__ void gather_kernel(const float* __restrict__ x,
                              const int* __restrict__ counts,
                              const int* __restrict__ offsets,
                              const int* __restrict__ bins,
                              float* __restrict__ out) {
    int cell = blockIdx.x * (blockDim.x >> 6) + (threadIdx.x >> 6);
    int lane = threadIdx.x & 63;
    if (cell >= NCELLS) return;

    int cnt = counts[cell];
    if (cnt == 0) return;                 // memset already zeroed out[]
    int off = offsets[cell];

    float a0 = 0.f, a1 = 0.f, a2 = 0.f, a3 = 0.f;
    int i = 0;
    for (; i + 4 <= cnt; i += 4) {
        int p0 = bins[off + i + 0];
        int p1 = bins[off + i + 1];
        int p2 = bins[off + i + 2];
        int p3 = bins[off + i + 3];
        a0 += x[(size_t)p0 * CC + lane];
        a1 += x[(size_t)p1 * CC + lane];
        a2 += x[(size_t)p2 * CC + lane];
        a3 += x[(size_t)p3 * CC + lane];
    }
    for (; i < cnt; ++i) {
        a0 += x[(size_t)bins[off + i] * CC + lane];
    }
    float s = (a0 + a1) + (a2 + a3);

    int yx = cell % (NYg * NXg);          // y*NX + x
    int bz = cell / (NYg * NXg);          // b*NZ + gz
    out[((size_t)bz * CC + lane) * CH_STRIDE + yx] = s;
}

// ---------------------------------------------------------------------------
extern "C" void kernel_launch(void* const* d_in, const int* in_sizes, int n_in,
                              void* d_out, int out_size, void* d_ws, size_t ws_size,
                              hipStream_t stream) {
    const float* x    = (const float*)d_in[0];
    const float* intr = (const float*)d_in[1];
    const float* pose = (const float*)d_in[2];
    float* out = (float*)d_out;

    int* sidx    = (int*)d_ws;                 // PTS
    int* counts  = sidx + PTS;                 // NCELLS
    int* offsets = counts + NCELLS;            // NCELLS
    int* cursor  = offsets + NCELLS;           // NCELLS
    int* bins    = cursor + NCELLS;            // PTS
    // total: 2*PTS + 3*NCELLS ints ~= 5.9 MB

    hipMemsetAsync(out, 0, (size_t)out_size * sizeof(float), stream);
    hipMemsetAsync(counts, 0, (size_t)NCELLS * sizeof(int), stream);

    geom_hist_kernel<<<(PTS + 255) / 256, 256, 0, stream>>>(intr, pose, sidx, counts);
    scan_kernel<<<1, 1024, 0, stream>>>(counts, offsets, cursor);
    fill_kernel<<<(PTS + 255) / 256, 256, 0, stream>>>(sidx, cursor, bins);
    gather_kernel<<<(NCELLS + 3) / 4, 256, 0, stream>>>(x, counts, offsets, bins, out);
}

// Round 3
// 386.178 us; speedup vs baseline: 3.2563x; 1.0551x over previous
//
#include <hip/hip_runtime.h>

// Problem constants
#define BB 2
#define NN 4
#define DD 48
#define HH 28
#define WW 60
#define CC 64
#define NXg 192
#define NYg 192
#define NZg 1
#define DOWNS 8

constexpr int PTS    = BB * NN * DD * HH * WW;       // 645120 points
constexpr int NCELLS = BB * NZg * NYg * NXg;         // 73728 output cells
constexpr int CH_STRIDE = NYg * NXg;                 // 36864 floats per channel plane

// ---------------------------------------------------------------------------
// Kernel A: per-point geometry -> cell id (or -1), histogram with wave-level
// run aggregation; atomicAdd return value = per-point rank within its cell
// (makes the later fill pass atomic-free).
// f64 to match the numpy reference's cell assignment at boundaries.
// ---------------------------------------------------------------------------
__global__ void geom_hist_kernel(const float* __restrict__ intr,
                                 const float* __restrict__ pose,
                                 int* __restrict__ sidx,
                                 int* __restrict__ rankv,
                                 int* __restrict__ counts) {
    int p = blockIdx.x * blockDim.x + threadIdx.x;   // grid is exact multiple
    int lane = threadIdx.x & 63;

    int w = p % WW;
    int t = p / WW;
    int h = t % HH; t /= HH;
    int d = t % DD; t /= DD;
    int n = t % NN;
    int b = t / NN;

    const float* K  = intr + (size_t)(b * NN + n) * 9;
    const float* Pm = pose + (size_t)(b * NN + n) * 16;

    double k00 = K[0], k01 = K[1], k02 = K[2];
    double k10 = K[3], k11 = K[4], k12 = K[5];
    double k20 = K[6], k21 = K[7], k22 = K[8];

    double det = k00 * (k11 * k22 - k12 * k21)
               - k01 * (k10 * k22 - k12 * k20)
               + k02 * (k10 * k21 - k11 * k20);
    double id = 1.0 / det;
    double i00 = (k11 * k22 - k12 * k21) * id;
    double i01 = (k02 * k21 - k01 * k22) * id;
    double i02 = (k01 * k12 - k02 * k11) * id;
    double i10 = (k12 * k20 - k10 * k22) * id;
    double i11 = (k00 * k22 - k02 * k20) * id;
    double i12 = (k02 * k10 - k00 * k12) * id;
    double i20 = (k10 * k21 - k11 * k20) * id;
    double i21 = (k01 * k20 - k00 * k21) * id;
    double i22 = (k00 * k11 - k01 * k10) * id;

    double r00 = Pm[0],  r01 = Pm[1],  r02 = Pm[2],  tx = Pm[3];
    double r10 = Pm[4],  r11 = Pm[5],  r12 = Pm[6],  ty = Pm[7];
    double r20 = Pm[8],  r21 = Pm[9],  r22 = Pm[10], tz = Pm[11];

    double c00 = r00 * i00 + r01 * i10 + r02 * i20;
    double c01 = r00 * i01 + r01 * i11 + r02 * i21;
    double c02 = r00 * i02 + r01 * i12 + r02 * i22;
    double c10 = r10 * i00 + r11 * i10 + r12 * i20;
    double c11 = r10 * i01 + r11 * i11 + r12 * i21;
    double c12 = r10 * i02 + r11 * i12 + r12 * i22;
    double c20 = r20 * i00 + r21 * i10 + r22 * i20;
    double c21 = r20 * i01 + r21 * i11 + r22 * i21;
    double c22 = r20 * i02 + r21 * i12 + r22 * i22;

    double u   = (double)w * ((double)(WW * DOWNS - 1) / (double)(WW - 1));
    double v   = (double)h * ((double)(HH * DOWNS - 1) / (double)(HH - 1));
    double dep = 2.0 + (double)d;
    double px = u * dep, py = v * dep, pz = dep;

    double gxf = (c00 * px + c01 * py + c02 * pz + tx) * 4.0 + 96.0;
    double gyf = (c10 * px + c11 * py + c12 * pz + ty) * 4.0 + 96.0;
    double gzf = ((c20 * px + c21 * py + c22 * pz + tz) + 10.0) / 20.0;

    int gx = (int)gxf;
    int gy = (int)gyf;
    int gz = (int)gzf;

    bool kept = (gx >= 0) & (gx < NXg) & (gy >= 0) & (gy < NYg) &
                (gz >= 0) & (gz < NZg);

    int cell = kept ? (((b * NZg + gz) * NYg + gy) * NXg + gx) : -1;

    // ---- wave-level run aggregation: one atomic per run of equal cells ----
    int prev = __shfl_up(cell, 1, 64);
    bool leader = (lane == 0) || (cell != prev);
    unsigned long long lead = __ballot(leader);
    unsigned long long below = lead & (~0ULL >> (63 - lane));
    int leaderLane = 63 - __clzll((long long)below);
    unsigned long long rest = (lane == 63) ? 0ULL : (lead >> (lane + 1));
    int next = rest ? (lane + 1 + (__ffsll(rest) - 1)) : 64;

    int base = 0;
    if (leader && cell >= 0) base = atomicAdd(&counts[cell], next - lane);
    base = __shfl(base, leaderLane, 64);

    sidx[p]  = cell;
    rankv[p] = base + (lane - leaderLane);   // garbage for culled; unused
}

// ---------------------------------------------------------------------------
// Kernel B: single-block parallel scan (1024 thr x 72 cells each) producing
// exclusive offsets AND a compacted worklist of non-empty cells (sorted).
// Packed 64-bit scan: high bits = count prefix, low 24 bits = nonzero prefix.
// ---------------------------------------------------------------------------
__global__ void __launch_bounds__(1024)
scan_compact_kernel(const int* __restrict__ counts,
                    int* __restrict__ offsets,
                    int* __restrict__ worklist,
                    int* __restrict__ nwork) {
    __shared__ long long wsum[16];
    int tid  = threadIdx.x;
    int lane = tid & 63, wv = tid >> 6;
    constexpr int PER = NCELLS / 1024;       // 72
    int base = tid * PER;

    const int4* c4 = (const int4*)(counts + base);
    int localCnt = 0, localNZ = 0;
    #pragma unroll
    for (int j = 0; j < PER / 4; ++j) {
        int4 vv = c4[j];
        localCnt += vv.x + vv.y + vv.z + vv.w;
        localNZ  += (vv.x > 0) + (vv.y > 0) + (vv.z > 0) + (vv.w > 0);
    }

    long long packed = ((long long)localCnt << 24) | (long long)localNZ;
    long long incl = packed;
    #pragma unroll
    for (int o = 1; o < 64; o <<= 1) {
        long long tt = __shfl_up(incl, o, 64);
        if (lane >= o) incl += tt;
    }
    if (lane == 63) wsum[wv] = incl;
    __syncthreads();
    if (tid == 0) {
        long long run = 0;
        #pragma unroll
        for (int k = 0; k < 16; ++k) { long long tt = wsum[k]; wsum[k] = run; run += tt; }
    }
    __syncthreads();
    long long excl = wsum[wv] + incl - packed;
    int run = (int)(excl >> 24);
    int nz  = (int)(excl & 0xFFFFFF);

    #pragma unroll
    for (int j = 0; j < PER / 4; ++j) {
        int4 vv = c4[j];                      // L2-resident re-read
        int i0 = base + 4 * j;
        offsets[i0 + 0] = run; if (vv.x > 0) worklist[nz++] = i0 + 0; run += vv.x;
        offsets[i0 + 1] = run; if (vv.y > 0) worklist[nz++] = i0 + 1; run += vv.y;
        offsets[i0 + 2] = run; if (vv.z > 0) worklist[nz++] = i0 + 2; run += vv.z;
        offsets[i0 + 3] = run; if (vv.w > 0) worklist[nz++] = i0 + 3; run += vv.w;
    }
    if (tid == 1023) *nwork = nz;
}

// ---------------------------------------------------------------------------
// Kernel C: atomic-free fill using precomputed ranks.
// ---------------------------------------------------------------------------
__global__ void fill_kernel(const int* __restrict__ sidx,
                            const int* __restrict__ rankv,
                            const int* __restrict__ offsets,
                            int* __restrict__ bins) {
    int p = blockIdx.x * blockDim.x + threadIdx.x;
    if (p >= PTS) return;
    int cell = sidx[p];
    if (cell < 0) return;
    bins[offsets[cell] + rankv[p]] = p;
}

// ---------------------------------------------------------------------------
// Kernel D: grid-stride over compacted worklist; one block (4 waves) per
// cell, lane = channel, 4-way split of the point list + LDS reduce.
// ---------------------------------------------------------------------------
__global__ void gather_kernel(const float* __restrict__ x,
                              const int* __restrict__ counts,
                              const int* __restrict__ offsets,
                              const int* __restrict__ bins,
                              const int* __restrict__ worklist,
                              const int* __restrict__ nwork,
                              float* __restrict__ out) {
    __shared__ float red[4][64];
    int lane = threadIdx.x & 63, wv = threadIdx.x >> 6;
    int n = *nwork;

    for (int j = blockIdx.x; j < n; j += gridDim.x) {
        int cell = worklist[j];
        int cnt  = counts[cell];
        int off  = offsets[cell];

        float a0 = 0.f, a1 = 0.f, a2 = 0.f, a3 = 0.f;
        for (int k = wv * 4; k < cnt; k += 16) {
            int p0 = bins[off + k];
            a0 += x[(size_t)p0 * CC + lane];
            if (k + 1 < cnt) a1 += x[(size_t)bins[off + k + 1] * CC + lane];
            if (k + 2 < cnt) a2 += x[(size_t)bins[off + k + 2] * CC + lane];
            if (k + 3 < cnt) a3 += x[(size_t)bins[off + k + 3] * CC + lane];
        }
        red[wv][lane] = (a0 + a1) + (a2 + a3);
        __syncthreads();
        if (wv == 0) {
            float s = red[0][lane] + red[1][lane] + red[2][lane] + red[3][lane];
            int yx = cell % (NYg * NXg);
            int bz = cell / (NYg * NXg);
            out[((size_t)bz * CC + lane) * CH_STRIDE + yx] = s;
        }
        __syncthreads();
    }
}

// ---------------------------------------------------------------------------
extern "C" void kernel_launch(void* const* d_in, const int* in_sizes, int n_in,
                              void* d_out, int out_size, void* d_ws, size_t ws_size,
                              hipStream_t stream) {
    const float* x    = (const float*)d_in[0];
    const float* intr = (const float*)d_in[1];
    const float* pose = (const float*)d_in[2];
    float* out = (float*)d_out;

    int* sidx     = (int*)d_ws;                // PTS
    int* rankv    = sidx + PTS;                // PTS
    int* counts   = rankv + PTS;               // NCELLS
    int* offsets  = counts + NCELLS;           // NCELLS
    int* worklist = offsets + NCELLS;          // NCELLS
    int* nwork    = worklist + NCELLS;         // 1
    int* bins     = nwork + 1;                 // PTS
    // total: 3*PTS + 3*NCELLS + 1 ints ~= 8.6 MB

    hipMemsetAsync(out, 0, (size_t)out_size * sizeof(float), stream);
    hipMemsetAsync(counts, 0, (size_t)NCELLS * sizeof(int), stream);

    geom_hist_kernel<<<PTS / 256, 256, 0, stream>>>(intr, pose, sidx, rankv, counts);
    scan_compact_kernel<<<1, 1024, 0, stream>>>(counts, offsets, worklist, nwork);
    fill_kernel<<<(PTS + 255) / 256, 256, 0, stream>>>(sidx, rankv, offsets, bins);
    gather_kernel<<<4096, 256, 0, stream>>>(x, counts, offsets, bins, worklist, nwork, out);
}